// Round 10
// baseline (5931.223 us; speedup 1.0000x reference)
//
#include <hip/hip_runtime.h>
#include <stdint.h>

#define NB 16
#define WIN 168
#define NSTEPS 24
#define NBLK (4096/NB)

typedef __attribute__((ext_vector_type(8))) short bf16x8;
typedef __attribute__((ext_vector_type(4))) float f32x4;

#if __has_builtin(__builtin_amdgcn_rcpf)
#define RCPF(x) __builtin_amdgcn_rcpf(x)
#else
#define RCPF(x) (1.0f / (x))
#endif
#if __has_builtin(__builtin_amdgcn_exp2f)
#define EXP2F(x) __builtin_amdgcn_exp2f(x)
#else
#define EXP2F(x) __expf((x) * 0.6931471805599453f)
#endif

__device__ __forceinline__ float sigm(float x){
  return RCPF(1.0f + EXP2F(x * -1.4426950408889634f));
}
__device__ __forceinline__ float sigtanh(float a, float b){
  float A = EXP2F(a * -1.4426950408889634f);
  float B = EXP2F(fabsf(b) * -2.8853900817779268f);
  float t = (1.0f - B) * RCPF((1.0f + A) * (1.0f + B));
  uint32_t sb = __builtin_bit_cast(uint32_t, b) & 0x80000000u;
  return __builtin_bit_cast(float, __builtin_bit_cast(uint32_t, t) ^ sb);
}

__device__ __forceinline__ uint32_t bf_rn(float f){
  uint32_t u = __builtin_bit_cast(uint32_t, f);
  return (u + 0x7FFFu + ((u >> 16) & 1u)) >> 16;
}
__device__ __forceinline__ float bf_f(uint32_t s){
  return __builtin_bit_cast(float, s << 16);
}
__device__ __forceinline__ void split_t(float f, uint32_t& hi, uint32_t& lo){
  uint32_t u = __builtin_bit_cast(uint32_t, f);
  hi = u >> 16;
  lo = bf_rn(f - bf_f(hi));
}
__device__ __forceinline__ void split_s(float f, short& hi, short& lo){
  uint32_t h = bf_rn(f);
  hi = (short)h;
  lo = (short)bf_rn(f - bf_f(h));
}
__device__ __forceinline__ f32x4 mfma16(bf16x8 a, bf16x8 b, f32x4 c){
  return __builtin_amdgcn_mfma_f32_16x16x32_bf16(a, b, c, 0, 0, 0);
}

__device__ __forceinline__ void lstm_epi(const f32x4 acc[4], float c[4], float hn[4]){
  #pragma unroll
  for (int r = 0; r < 4; r++){
    float cn = __builtin_fmaf(sigm(acc[1][r]), c[r], sigtanh(acc[0][r], acc[2][r]));
    c[r] = cn;
    hn[r] = sigtanh(acc[3][r], cn);
  }
}

#define FROW 136
#define FBLK 544
#define FB(buf,hl,kt) ((((buf)*2 + (hl))*2 + (kt)) * FBLK)
#define BUF_INTS (2*FBLK)

#define LGKM_FENCE() __asm__ volatile("s_waitcnt lgkmcnt(0)" ::: "memory")
#define VM_FENCE()   __asm__ volatile("s_waitcnt vmcnt(0)" ::: "memory")
#define CC_FENCE()   __asm__ volatile("" ::: "memory")

// ============================================================================
// DECOUPLED-BARRIER kernel: 256 blocks x 512 thr. Waves 0-3 = LSTM1 (A),
// waves 4-7 = LSTM2+FC (B) -- same roles as R7/R9, but the full-block
// __syncthreads is replaced by two 4-wave LDS soft barriers (barA / barB) so
// A and B waves free-run with DECORRELATED phase schedules. SIMD k hosts wave
// k (A) + wave k+4 (B): one wave's epilogue fills the other's MFMA stalls.
// Cross-type sync:
//   - A step (sg,t) throttles on barB >= 4*((sg-1)*169 + t+1)  [B consumed
//     hist slot t of sweep sg-1]; t==167 uses 4*169*sg [B's FC done -> win_s].
//   - B sweep sb gates on barA >= 4*168*(sb+1) [A finished sweep sb; A drains
//     vmcnt(0) before its last bump so hist/cS/aS[0] are visible -- same CU].
// A runs exactly one sweep ahead of B, rate-matched to B by the throttle.
// ============================================================================
__global__ __launch_bounds__(512, 2) void lstm_decoupled_kernel(
  const float* __restrict__ x,    const float* __restrict__ Wih1, const float* __restrict__ Whh1,
  const float* __restrict__ bih1, const float* __restrict__ bhh1,
  const float* __restrict__ Wih2, const float* __restrict__ Whh2,
  const float* __restrict__ bih2, const float* __restrict__ bhh2,
  const float* __restrict__ fc1w, const float* __restrict__ fc1b,
  const float* __restrict__ fc2w, const float* __restrict__ fc2b,
  float* __restrict__ out, short* __restrict__ hist)
{
  __shared__ __align__(16) short aS[2*2*2*FBLK];   // LSTM1 state dbuf
  __shared__ __align__(16) short bS[2*2*2*FBLK];   // LSTM2 state dbuf
  __shared__ float cS[64][16];                     // c1-final handoff A->B
  __shared__ float win_s[WIN][NB];
  __shared__ float Hlast[NB][68];
  __shared__ float fc1w_s[64*68];
  __shared__ float dval_s[NB];
  __shared__ int barA, barB;

  const int tid = threadIdx.x;
  const int wv8 = tid >> 6;          // 0..7
  const int wv  = wv8 & 3;
  const bool isA = (wv8 < 4);
  const int ln  = tid & 63;
  const int q   = ln >> 4;
  const int n   = ln & 15;
  const int bg0 = blockIdx.x * NB;
  const int u0  = 16*wv + 4*q;
  const int kt_  = u0 >> 5;
  const int q2_  = (u0 >> 3) & 3;
  const int jj0_ = u0 & 7;
  const int rdo  = q*FROW + n*8;
  const int wro  = q2_*FROW + n*8 + jj0_;
  const int gwo  = kt_*512 + q2_*128 + n*8 + jj0_;
  const int ro   = q*128 + n*8;
  short* __restrict__ hblk = hist + (size_t)blockIdx.x * WIN * 2048;

  for (int i = tid; i < WIN*NB; i += 512){ int t = i >> 4, b = i & 15; win_s[t][b] = x[(bg0 + b)*169 + t]; }
  for (int i = tid; i < 64*65; i += 512){ int j = i / 65, k = i % 65; fc1w_s[j*68 + k] = fc1w[i]; }
  if (tid < NB) dval_s[tid] = x[(bg0 + tid)*169 + 168];
  if (tid == 0){ barA = 0; barB = 0; }

  const float fc1b_r = fc1b[ln];
  const float fc2w_r = fc2w[ln];
  const float fc2b_r = fc2b[0];

  __syncthreads();   // staging + counter init; ONLY full-block barrier.

  volatile int* vA = &barA;
  volatile int* vB = &barB;

  if (isA){
    // =================== A: LSTM1 producer ===================
    bf16x8 A1hi[4][2], A1lo[4][2], Ain1[4];
    f32x4 b1c[4];
    #pragma unroll
    for (int e = 0; e < 4; e++){
      const int ja = 64*e + 16*wv + n;
      #pragma unroll
      for (int kt = 0; kt < 2; kt++){
        const float* pw = Whh1 + ja*64 + kt*32 + q*8;
        #pragma unroll
        for (int jj = 0; jj < 8; jj++){ short h,l; split_s(pw[jj], h, l); A1hi[e][kt][jj] = h; A1lo[e][kt][jj] = l; }
      }
      bf16x8 ain = {0,0,0,0,0,0,0,0};
      if (q == 0){ short wh, wl; split_s(Wih1[ja], wh, wl); ain[0] = wh; ain[1] = wh; ain[2] = wl; }
      Ain1[e] = ain;
      const int jc = 64*e + u0;
      #pragma unroll
      for (int r = 0; r < 4; r++) b1c[e][r] = bih1[jc+r] + bhh1[jc+r];
    }
    float c1[4];
    int gA = 0;

    for (int sg = 0; sg < NSTEPS; sg++){
      #pragma unroll
      for (int r = 0; r < 4; r++) c1[r] = 0.0f;
      int slot = sg;
      for (int t = 0; t < WIN; t++){
        // ---- phase entry: intra-A barrier + anti-dependency throttle on B
        int tb = 0;
        if (sg > 0) tb = (t == WIN-1) ? 4*169*sg : 4*((sg-1)*169 + t + 1);
        if (ln == 0){
          const int ta = 4*gA;
          while (*vA < ta) {}
          while (*vB < tb) {}
        }
        CC_FENCE();
        // ---- LSTM1 step
        {
          const int rb = t & 1, wb = rb ^ 1;
          f32x4 acc[4];
          bf16x8 bin = {0,0,0,0,0,0,0,0};
          { float xv = win_s[slot][n]; uint32_t xh, xl; split_t(xv, xh, xl);
            if (q == 0){ bin[0] = (short)xh; bin[1] = (short)xl; bin[2] = (short)xh; } }
          if (t == 0){
            #pragma unroll
            for (int e = 0; e < 4; e++) acc[e] = mfma16(Ain1[e], bin, b1c[e]);
          } else {
            bf16x8 Bh0 = *(const bf16x8*)&aS[FB(rb,0,0)+rdo];
            bf16x8 Bl0 = *(const bf16x8*)&aS[FB(rb,1,0)+rdo];
            bf16x8 Bh1 = *(const bf16x8*)&aS[FB(rb,0,1)+rdo];
            bf16x8 Bl1 = *(const bf16x8*)&aS[FB(rb,1,1)+rdo];
            #pragma unroll
            for (int e = 0; e < 4; e++){
              f32x4 a = b1c[e];
              a = mfma16(A1hi[e][0], Bh0, a);
              a = mfma16(A1hi[e][0], Bl0, a);
              a = mfma16(A1lo[e][0], Bh0, a);
              a = mfma16(A1hi[e][1], Bh1, a);
              a = mfma16(A1hi[e][1], Bl1, a);
              a = mfma16(A1lo[e][1], Bh1, a);
              a = mfma16(Ain1[e], bin, a);
              acc[e] = a;
            }
          }
          float hn[4];
          lstm_epi(acc, c1, hn);
          uint32_t ph[4], pl[4];
          #pragma unroll
          for (int r = 0; r < 4; r++) split_t(hn[r], ph[r], pl[r]);
          *(uint2*)&aS[FB(wb,0,kt_)+wro] = make_uint2(ph[0] | (ph[1]<<16), ph[2] | (ph[3]<<16));
          *(uint2*)&aS[FB(wb,1,kt_)+wro] = make_uint2(pl[0] | (pl[1]<<16), pl[2] | (pl[3]<<16));
          uint32_t sh[4], sl[4];
          #pragma unroll
          for (int r = 0; r < 4; r++){ bool pos = hn[r] > 0.0f; sh[r] = pos ? ph[r] : 0u; sl[r] = pos ? pl[r] : 0u; }
          short* Hp = hblk + (size_t)t * 2048;
          *(uint2*)&Hp[gwo]        = make_uint2(sh[0] | (sh[1]<<16), sh[2] | (sh[3]<<16));
          *(uint2*)&Hp[1024 + gwo] = make_uint2(sl[0] | (sl[1]<<16), sl[2] | (sl[3]<<16));
          if (t == WIN-1){
            #pragma unroll
            for (int r = 0; r < 4; r++) cS[u0 + r][n] = c1[r];
          }
        }
        // ---- phase exit: LDS release; at sweep end also drain hist stores
        LGKM_FENCE();
        if (t == WIN-1) VM_FENCE();
        if (ln == 0) atomicAdd(&barA, 1);
        gA++;
        slot++; if (slot == WIN) slot = 0;
      }
    }

  } else {
    // =================== B: LSTM2 + FC consumer ===================
    bf16x8 A2hi[4][4], A2lo[4][4];
    f32x4 b2c[4];
    #pragma unroll
    for (int e = 0; e < 4; e++){
      const int ja = 64*e + 16*wv + n;
      #pragma unroll
      for (int kt = 0; kt < 4; kt++){
        const float* pw = (kt < 2 ? (Wih2 + ja*64 + kt*32) : (Whh2 + ja*64 + (kt-2)*32)) + q*8;
        #pragma unroll
        for (int jj = 0; jj < 8; jj++){ short h,l; split_s(pw[jj], h, l); A2hi[e][kt][jj] = h; A2lo[e][kt][jj] = l; }
      }
      const int jc = 64*e + u0;
      #pragma unroll
      for (int r = 0; r < 4; r++) b2c[e][r] = bih2[jc+r] + bhh2[jc+r];
    }
    float c2[4];
    bf16x8 ch0, cl0, ch1, cl1, nh0, nl0, nh1, nl1;
    int gB = 0;

    auto loadn = [&](int t){
      const short* Hp = hblk + (size_t)t * 2048;
      nh0 = *(const bf16x8*)&Hp[ro];
      nl0 = *(const bf16x8*)&Hp[1024 + ro];
      nh1 = *(const bf16x8*)&Hp[512 + ro];
      nl1 = *(const bf16x8*)&Hp[1536 + ro];
    };

    for (int sb = 0; sb < NSTEPS; sb++){
      for (int t = 0; t < WIN; t++){
        // ---- phase entry: intra-B barrier; at t==0 gate on A's sweep
        if (ln == 0){
          const int tb = 4*gB;
          while (*vB < tb) {}
          if (t == 0){ const int ta = 4*168*(sb+1); while (*vA < ta) {} }
        }
        CC_FENCE();
        if (t == 0){
          #pragma unroll
          for (int r = 0; r < 4; r++) c2[r] = cS[u0 + r][n];
          const short* Hp = hblk;            // slot 0
          ch0 = *(const bf16x8*)&Hp[ro];
          cl0 = *(const bf16x8*)&Hp[1024 + ro];
          ch1 = *(const bf16x8*)&Hp[512 + ro];
          cl1 = *(const bf16x8*)&Hp[1536 + ro];
          loadn(1);
        } else if (t < WIN-1){
          loadn(t + 1);                      // hoisted prefetch (R9)
        }
        // ---- LSTM2 step
        {
          const bool last = (t == WIN-1);
          const short* Sr = (t == 0) ? aS : bS;
          const int rb = (t == 0) ? 0 : (t & 1);
          const int wb = (t == 0) ? 1 : ((t & 1) ^ 1);
          bf16x8 L2h0 = *(const bf16x8*)&Sr[FB(rb,0,0)+rdo];
          bf16x8 L2l0 = *(const bf16x8*)&Sr[FB(rb,1,0)+rdo];
          bf16x8 L2h1 = *(const bf16x8*)&Sr[FB(rb,0,1)+rdo];
          bf16x8 L2l1 = *(const bf16x8*)&Sr[FB(rb,1,1)+rdo];
          f32x4 acc[4];
          #pragma unroll
          for (int e = 0; e < 4; e++){
            f32x4 a = b2c[e];
            a = mfma16(A2hi[e][0], ch0, a);
            a = mfma16(A2hi[e][0], cl0, a);
            a = mfma16(A2lo[e][0], ch0, a);
            a = mfma16(A2hi[e][1], ch1, a);
            a = mfma16(A2hi[e][1], cl1, a);
            a = mfma16(A2lo[e][1], ch1, a);
            a = mfma16(A2hi[e][2], L2h0, a);
            a = mfma16(A2hi[e][2], L2l0, a);
            a = mfma16(A2lo[e][2], L2h0, a);
            a = mfma16(A2hi[e][3], L2h1, a);
            a = mfma16(A2hi[e][3], L2l1, a);
            a = mfma16(A2lo[e][3], L2h1, a);
            acc[e] = a;
          }
          float hn[4];
          lstm_epi(acc, c2, hn);
          if (!last){
            uint32_t ph[4], pl[4];
            #pragma unroll
            for (int r = 0; r < 4; r++) split_t(hn[r], ph[r], pl[r]);
            *(uint2*)&bS[FB(wb,0,kt_)+wro] = make_uint2(ph[0] | (ph[1]<<16), ph[2] | (ph[3]<<16));
            *(uint2*)&bS[FB(wb,1,kt_)+wro] = make_uint2(pl[0] | (pl[1]<<16), pl[2] | (pl[3]<<16));
          } else {
            #pragma unroll
            for (int r = 0; r < 4; r++) Hlast[n][u0 + r] = fmaxf(hn[r], 0.0f);
          }
          ch0 = nh0; cl0 = nl0; ch1 = nh1; cl1 = nl1;
        }
        // ---- phase exit
        LGKM_FENCE();
        if (ln == 0) atomicAdd(&barB, 1);
        gB++;
      }
      // ---- FC phase (phase index 168 of this sweep)
      if (ln == 0){ const int tb = 4*gB; while (*vB < tb) {} }
      CC_FENCE();
      {
        float o4[4];
        #pragma unroll
        for (int bi = 0; bi < 4; bi++){
          const int b = 4*wv + bi;
          float a1 = fc1b_r;
          #pragma unroll
          for (int k4 = 0; k4 < 16; k4++){
            const float* wp = &fc1w_s[ln*68 + k4*4];
            const float* hp = &Hlast[b][k4*4];
            a1 += wp[0]*hp[0] + wp[1]*hp[1] + wp[2]*hp[2] + wp[3]*hp[3];
          }
          a1 += dval_s[b] * fc1w_s[ln*68 + 64];
          float v = a1 * fc2w_r;
          #pragma unroll
          for (int off = 32; off > 0; off >>= 1) v += __shfl_xor(v, off);
          o4[bi] = v + fc2b_r;
        }
        if (ln == 0){
          #pragma unroll
          for (int bi = 0; bi < 4; bi++){
            const int b = 4*wv + bi;
            out[(bg0 + b)*24 + sb] = o4[bi];
            win_s[sb][b] = o4[bi];           // sb < 24 < WIN
          }
        }
      }
      LGKM_FENCE();
      if (ln == 0) atomicAdd(&barB, 1);
      gB++;
    }
  }
}

// ============================================================================
// Fallback (no workspace): replay scheme, 256 threads. Safety only.
// ============================================================================
__global__ __launch_bounds__(256, 1) void lstm_fallback_kernel(
  const float* __restrict__ x,    const float* __restrict__ Wih1, const float* __restrict__ Whh1,
  const float* __restrict__ bih1, const float* __restrict__ bhh1,
  const float* __restrict__ Wih2, const float* __restrict__ Whh2,
  const float* __restrict__ bih2, const float* __restrict__ bhh2,
  const float* __restrict__ fc1w, const float* __restrict__ fc1b,
  const float* __restrict__ fc2w, const float* __restrict__ fc2b,
  float* __restrict__ out)
{
  __shared__ __align__(16) short aS[2*2*2*FBLK];
  __shared__ __align__(16) short r1f[2*2*2*FBLK];
  __shared__ __align__(16) short rlf[2*2*2*FBLK];
  __shared__ float win_s[WIN][NB];
  __shared__ float Hlast[NB][68];
  __shared__ float fc1w_s[64*68];
  __shared__ float dval_s[NB];

  const int tid = threadIdx.x;
  const int wv  = tid >> 6;
  const int ln  = tid & 63;
  const int q   = ln >> 4;
  const int n   = ln & 15;
  const int bg0 = blockIdx.x * NB;
  const int u0  = 16*wv + 4*q;
  const int kt_  = u0 >> 5;
  const int q2_  = (u0 >> 3) & 3;
  const int jj0_ = u0 & 7;
  const int rdo  = q*FROW + n*8;
  const int wro  = q2_*FROW + n*8 + jj0_;

  for (int i = tid; i < WIN*NB; i += 256){ int t = i >> 4, b = i & 15; win_s[t][b] = x[(bg0 + b)*169 + t]; }
  for (int i = tid; i < 64*65; i += 256){ int j = i / 65, k = i % 65; fc1w_s[j*68 + k] = fc1w[i]; }
  if (tid < NB) dval_s[tid] = x[(bg0 + tid)*169 + 168];

  const float fc1b_r = fc1b[ln];
  const float fc2w_r = fc2w[ln];
  const float fc2b_r = fc2b[0];

  bf16x8 A1hi[4][2], A1lo[4][2], Ain1[4];
  bf16x8 A2hi[4][4], A2lo[4][4];
  f32x4 b1c[4], b2c[4];
  #pragma unroll
  for (int e = 0; e < 4; e++){
    const int ja = 64*e + 16*wv + n;
    #pragma unroll
    for (int kt = 0; kt < 2; kt++){
      const float* pw = Whh1 + ja*64 + kt*32 + q*8;
      #pragma unroll
      for (int jj = 0; jj < 8; jj++){ short h,l; split_s(pw[jj], h, l); A1hi[e][kt][jj] = h; A1lo[e][kt][jj] = l; }
    }
    #pragma unroll
    for (int kt = 0; kt < 4; kt++){
      const float* pw = (kt < 2 ? (Wih2 + ja*64 + kt*32) : (Whh2 + ja*64 + (kt-2)*32)) + q*8;
      #pragma unroll
      for (int jj = 0; jj < 8; jj++){ short h,l; split_s(pw[jj], h, l); A2hi[e][kt][jj] = h; A2lo[e][kt][jj] = l; }
    }
    bf16x8 ain = {0,0,0,0,0,0,0,0};
    if (q == 0){ short wh, wl; split_s(Wih1[ja], wh, wl); ain[0] = wh; ain[1] = wh; ain[2] = wl; }
    Ain1[e] = ain;
    const int jc = 64*e + u0;
    #pragma unroll
    for (int r = 0; r < 4; r++){
      b1c[e][r] = bih1[jc+r] + bhh1[jc+r];
      b2c[e][r] = bih2[jc+r] + bhh2[jc+r];
    }
  }

  float c1[4], c2[4], c1r[4];

  auto lstm1_step = [&](short* S, float* cst, int rb, int wb, int slot, bool relu_out){
    bf16x8 Bh0 = *(const bf16x8*)&S[FB(rb,0,0)+rdo];
    bf16x8 Bl0 = *(const bf16x8*)&S[FB(rb,1,0)+rdo];
    bf16x8 Bh1 = *(const bf16x8*)&S[FB(rb,0,1)+rdo];
    bf16x8 Bl1 = *(const bf16x8*)&S[FB(rb,1,1)+rdo];
    bf16x8 bin = {0,0,0,0,0,0,0,0};
    { float xv = win_s[slot][n]; uint32_t xh, xl; split_t(xv, xh, xl);
      if (q == 0){ bin[0] = (short)xh; bin[1] = (short)xl; bin[2] = (short)xh; } }
    f32x4 acc[4];
    #pragma unroll
    for (int e = 0; e < 4; e++){
      f32x4 a = b1c[e];
      a = mfma16(A1hi[e][0], Bh0, a);
      a = mfma16(A1hi[e][0], Bl0, a);
      a = mfma16(A1lo[e][0], Bh0, a);
      a = mfma16(A1hi[e][1], Bh1, a);
      a = mfma16(A1hi[e][1], Bl1, a);
      a = mfma16(A1lo[e][1], Bh1, a);
      a = mfma16(Ain1[e], bin, a);
      acc[e] = a;
    }
    float hn[4];
    lstm_epi(acc, cst, hn);
    uint32_t ph[4], pl[4];
    #pragma unroll
    for (int r = 0; r < 4; r++) split_t(hn[r], ph[r], pl[r]);
    *(uint2*)&S[FB(wb,0,kt_)+wro] = make_uint2(ph[0] | (ph[1]<<16), ph[2] | (ph[3]<<16));
    *(uint2*)&S[FB(wb,1,kt_)+wro] = make_uint2(pl[0] | (pl[1]<<16), pl[2] | (pl[3]<<16));
    if (relu_out){
      uint32_t sh[4], sl[4];
      #pragma unroll
      for (int r = 0; r < 4; r++){ bool pos = hn[r] > 0.0f; sh[r] = pos ? ph[r] : 0u; sl[r] = pos ? pl[r] : 0u; }
      *(uint2*)&rlf[FB(rb,0,kt_)+wro] = make_uint2(sh[0] | (sh[1]<<16), sh[2] | (sh[3]<<16));
      *(uint2*)&rlf[FB(rb,1,kt_)+wro] = make_uint2(sl[0] | (sl[1]<<16), sl[2] | (sl[3]<<16));
    }
  };

  auto lstm2_core = [&](bf16x8 L1h0, bf16x8 L1l0, bf16x8 L1h1, bf16x8 L1l1,
                        int rbuf, int wbuf, bool last){
    bf16x8 L2h0 = *(const bf16x8*)&aS[FB(rbuf,0,0)+rdo];
    bf16x8 L2l0 = *(const bf16x8*)&aS[FB(rbuf,1,0)+rdo];
    bf16x8 L2h1 = *(const bf16x8*)&aS[FB(rbuf,0,1)+rdo];
    bf16x8 L2l1 = *(const bf16x8*)&aS[FB(rbuf,1,1)+rdo];
    f32x4 acc[4];
    #pragma unroll
    for (int e = 0; e < 4; e++){
      f32x4 a = b2c[e];
      a = mfma16(A2hi[e][0], L1h0, a);
      a = mfma16(A2hi[e][0], L1l0, a);
      a = mfma16(A2lo[e][0], L1h0, a);
      a = mfma16(A2hi[e][1], L1h1, a);
      a = mfma16(A2hi[e][1], L1l1, a);
      a = mfma16(A2lo[e][1], L1h1, a);
      a = mfma16(A2hi[e][2], L2h0, a);
      a = mfma16(A2hi[e][2], L2l0, a);
      a = mfma16(A2lo[e][2], L2h0, a);
      a = mfma16(A2hi[e][3], L2h1, a);
      a = mfma16(A2hi[e][3], L2l1, a);
      a = mfma16(A2lo[e][3], L2h1, a);
      acc[e] = a;
    }
    float hn[4];
    lstm_epi(acc, c2, hn);
    if (!last){
      uint32_t ph[4], pl[4];
      #pragma unroll
      for (int r = 0; r < 4; r++) split_t(hn[r], ph[r], pl[r]);
      *(uint2*)&aS[FB(wbuf,0,kt_)+wro] = make_uint2(ph[0] | (ph[1]<<16), ph[2] | (ph[3]<<16));
      *(uint2*)&aS[FB(wbuf,1,kt_)+wro] = make_uint2(pl[0] | (pl[1]<<16), pl[2] | (pl[3]<<16));
    } else {
      #pragma unroll
      for (int r = 0; r < 4; r++) Hlast[n][u0 + r] = fmaxf(hn[r], 0.0f);
    }
  };

  for (int s = 0; s < NSTEPS; s++){
    { int* p = (int*)&aS[0];
      for (int i = tid; i < BUF_INTS; i += 256) p[i] = 0; }
    #pragma unroll
    for (int r = 0; r < 4; r++) c1[r] = 0.0f;
    int slot = s;
    for (int t = 0; t < WIN; t++){
      __syncthreads();
      lstm1_step(aS, c1, t & 1, (t & 1) ^ 1, slot, false);
      slot++; if (slot == WIN) slot = 0;
    }
    #pragma unroll
    for (int r = 0; r < 4; r++){ c2[r] = c1[r]; c1r[r] = 0.0f; }
    { int* p = (int*)&r1f[0];
      for (int i = tid; i < BUF_INTS; i += 256) p[i] = 0; }
    slot = s;
    __syncthreads();
    lstm1_step(r1f, c1r, 0, 1, slot, true);
    slot++;
    for (int i = 1; i < WIN; i++){
      __syncthreads();
      const int rb = i & 1, wb = rb ^ 1;
      lstm1_step(r1f, c1r, rb, wb, slot, true);
      bf16x8 L1h0 = *(const bf16x8*)&rlf[FB(wb,0,0)+rdo];
      bf16x8 L1l0 = *(const bf16x8*)&rlf[FB(wb,1,0)+rdo];
      bf16x8 L1h1 = *(const bf16x8*)&rlf[FB(wb,0,1)+rdo];
      bf16x8 L1l1 = *(const bf16x8*)&rlf[FB(wb,1,1)+rdo];
      lstm2_core(L1h0, L1l0, L1h1, L1l1, wb, rb, false);
      slot++; if (slot == WIN) slot = 0;
    }
    __syncthreads();
    {
      const int rb = (WIN - 1) & 1;
      bf16x8 L1h0 = *(const bf16x8*)&rlf[FB(rb,0,0)+rdo];
      bf16x8 L1l0 = *(const bf16x8*)&rlf[FB(rb,1,0)+rdo];
      bf16x8 L1h1 = *(const bf16x8*)&rlf[FB(rb,0,1)+rdo];
      bf16x8 L1l1 = *(const bf16x8*)&rlf[FB(rb,1,1)+rdo];
      lstm2_core(L1h0, L1l0, L1h1, L1l1, rb, 0, true);
    }
    __syncthreads();
    {
      float o4[4];
      #pragma unroll
      for (int bi = 0; bi < 4; bi++){
        const int b = 4*wv + bi;
        float a1 = fc1b_r;
        #pragma unroll
        for (int k4 = 0; k4 < 16; k4++){
          const float* wp = &fc1w_s[ln*68 + k4*4];
          const float* hp = &Hlast[b][k4*4];
          a1 += wp[0]*hp[0] + wp[1]*hp[1] + wp[2]*hp[2] + wp[3]*hp[3];
        }
        a1 += dval_s[b] * fc1w_s[ln*68 + 64];
        float v = a1 * fc2w_r;
        #pragma unroll
        for (int off = 32; off > 0; off >>= 1) v += __shfl_xor(v, off);
        o4[bi] = v + fc2b_r;
      }
      if (ln == 0){
        #pragma unroll
        for (int bi = 0; bi < 4; bi++){
          const int b = 4*wv + bi;
          out[(bg0 + b)*24 + s] = o4[bi];
          win_s[s % WIN][b] = o4[bi];
        }
      }
    }
  }
}

extern "C" void kernel_launch(void* const* d_in, const int* in_sizes, int n_in,
                              void* d_out, int out_size, void* d_ws, size_t ws_size,
                              hipStream_t stream) {
  (void)in_sizes; (void)n_in; (void)out_size;
  const size_t need = (size_t)NBLK * WIN * 2048 * sizeof(short);   // ~176 MB
  if (ws_size >= need){
    lstm_decoupled_kernel<<<dim3(NBLK), dim3(512), 0, stream>>>(
        (const float*)d_in[0], (const float*)d_in[1], (const float*)d_in[2],
        (const float*)d_in[3], (const float*)d_in[4], (const float*)d_in[5],
        (const float*)d_in[6], (const float*)d_in[7], (const float*)d_in[8],
        (const float*)d_in[9], (const float*)d_in[10], (const float*)d_in[11],
        (const float*)d_in[12], (float*)d_out, (short*)d_ws);
  } else {
    lstm_fallback_kernel<<<dim3(NBLK), dim3(256), 0, stream>>>(
        (const float*)d_in[0], (const float*)d_in[1], (const float*)d_in[2],
        (const float*)d_in[3], (const float*)d_in[4], (const float*)d_in[5],
        (const float*)d_in[6], (const float*)d_in[7], (const float*)d_in[8],
        (const float*)d_in[9], (const float*)d_in[10], (const float*)d_in[11],
        (const float*)d_in[12], (float*)d_out);
  }
}

// Round 11
// 5224.162 us; speedup vs baseline: 1.1353x; 1.1353x over previous
//
#include <hip/hip_runtime.h>
#include <stdint.h>

#define NB 16
#define WIN 168
#define NSTEPS 24
#define NBLK (4096/NB)
#define NT 512

typedef __attribute__((ext_vector_type(8))) short bf16x8;
typedef __attribute__((ext_vector_type(4))) float f32x4;

#if __has_builtin(__builtin_amdgcn_rcpf)
#define RCPF(x) __builtin_amdgcn_rcpf(x)
#else
#define RCPF(x) (1.0f / (x))
#endif
#if __has_builtin(__builtin_amdgcn_exp2f)
#define EXP2F(x) __builtin_amdgcn_exp2f(x)
#else
#define EXP2F(x) __expf((x) * 0.6931471805599453f)
#endif

__device__ __forceinline__ float sigm(float x){
  return RCPF(1.0f + EXP2F(x * -1.4426950408889634f));
}
__device__ __forceinline__ float sigtanh(float a, float b){
  float A = EXP2F(a * -1.4426950408889634f);
  float B = EXP2F(fabsf(b) * -2.8853900817779268f);
  float t = (1.0f - B) * RCPF((1.0f + A) * (1.0f + B));
  uint32_t sb = __builtin_bit_cast(uint32_t, b) & 0x80000000u;
  return __builtin_bit_cast(float, __builtin_bit_cast(uint32_t, t) ^ sb);
}

__device__ __forceinline__ uint32_t bf_rn(float f){
  uint32_t u = __builtin_bit_cast(uint32_t, f);
  return (u + 0x7FFFu + ((u >> 16) & 1u)) >> 16;
}
__device__ __forceinline__ float bf_f(uint32_t s){
  return __builtin_bit_cast(float, s << 16);
}
__device__ __forceinline__ void split_t(float f, uint32_t& hi, uint32_t& lo){
  uint32_t u = __builtin_bit_cast(uint32_t, f);
  hi = u >> 16;
  lo = bf_rn(f - bf_f(hi));
}
__device__ __forceinline__ void split_s(float f, short& hi, short& lo){
  uint32_t h = bf_rn(f);
  hi = (short)h;
  lo = (short)bf_rn(f - bf_f(h));
}
__device__ __forceinline__ f32x4 mfma16(bf16x8 a, bf16x8 b, f32x4 c){
  return __builtin_amdgcn_mfma_f32_16x16x32_bf16(a, b, c, 0, 0, 0);
}

__device__ __forceinline__ void lstm_epi(const f32x4 acc[4], float c[4], float hn[4]){
  #pragma unroll
  for (int r = 0; r < 4; r++){
    float cn = __builtin_fmaf(sigm(acc[1][r]), c[r], sigtanh(acc[0][r], acc[2][r]));
    c[r] = cn;
    hn[r] = sigtanh(acc[3][r], cn);
  }
}

#define FROW 136
#define FBLK 544
#define FB(buf,hl,kt) ((((buf)*2 + (hl))*2 + (kt)) * FBLK)
#define BUF_INTS (2*FBLK)

// partial-buffer LDS strides (floats)
#define PS_E   256          // 4(q)*16(n)*4(f32x4)
#define PS_WV  (4*PS_E)
#define PS_PB  (4*PS_WV)

// ============================================================================
// R11: REBALANCED wave-specialized kernel (R9 base, barrier schedule
// unchanged). A-waves (0-3): LSTM1 (28 MFMA + epi) PLUS LSTM2's entire
// L1-contribution as fp32 partials (24 MFMA, independent of A's epilogue ->
// intra-wave ILP). B-waves (4-7): C-init from partial + 24 L2-MFMA + epi +
// FC. Partials move through pS (32 KB LDS, double-buffered by step parity);
// A-wave wv's C-frag lane mapping == B-wave wv's, so transfer is
// lane-aligned b128. Accumulation order preserved exactly: partial = b2c +
// L1kt0(3 terms) + L1kt1(3 terms); B continues L2kt0(3) + L2kt1(3).
// Bit-exact vs R9 (absmax must be exactly 2.441406e-4).
// Partial(t) for B's step t of sweep s is computed by A during the previous
// barrier slot, reading hist slot t (sweep s data: slots > current A-write
// index still hold old sweep). Hist is now read by A instead of B -- same
// traffic, single consumer.
// ============================================================================
__global__ __launch_bounds__(NT, 2) void lstm_fused_kernel(
  const float* __restrict__ x,    const float* __restrict__ Wih1, const float* __restrict__ Whh1,
  const float* __restrict__ bih1, const float* __restrict__ bhh1,
  const float* __restrict__ Wih2, const float* __restrict__ Whh2,
  const float* __restrict__ bih2, const float* __restrict__ bhh2,
  const float* __restrict__ fc1w, const float* __restrict__ fc1b,
  const float* __restrict__ fc2w, const float* __restrict__ fc2b,
  float* __restrict__ out, short* __restrict__ hist)
{
  __shared__ __align__(16) short aS[2*2*2*FBLK];   // LSTM1 state dbuf
  __shared__ __align__(16) short bS[2*2*2*FBLK];   // LSTM2 state dbuf
  __shared__ __align__(16) float pS[2*PS_PB];      // LSTM2 partial dbuf (32 KB)
  __shared__ float cS[64][16];                     // c1-final handoff A->B
  __shared__ float win_s[WIN][NB];
  __shared__ float Hlast[NB][68];
  __shared__ float fc1w_s[64*68];
  __shared__ float dval_s[NB];

  const int tid = threadIdx.x;
  const int wv8 = tid >> 6;          // 0..7
  const int wv  = wv8 & 3;           // role-local wave id 0..3
  const bool isA = (wv8 < 4);
  const int ln  = tid & 63;
  const int q   = ln >> 4;
  const int n   = ln & 15;
  const int bg0 = blockIdx.x * NB;
  const int u0  = 16*wv + 4*q;
  const int kt_  = u0 >> 5;
  const int q2_  = (u0 >> 3) & 3;
  const int jj0_ = u0 & 7;                          // {0,4}
  const int rdo  = q*FROW + n*8;                    // frag read offset
  const int wro  = q2_*FROW + n*8 + jj0_;           // frag write offset
  const int gwo  = kt_*512 + q2_*128 + n*8 + jj0_;  // hist write offset
  const int ro   = q*128 + n*8;                     // hist read offset
  const int pso  = wv*PS_WV + q*64 + n*4;           // partial lane offset (+e*PS_E, +pb*PS_PB)
  short* __restrict__ hblk = hist + (size_t)blockIdx.x * WIN * 2048;

  for (int i = tid; i < WIN*NB; i += NT){ int t = i >> 4, b = i & 15; win_s[t][b] = x[(bg0 + b)*169 + t]; }
  for (int i = tid; i < 64*65; i += NT){ int j = i / 65, k = i % 65; fc1w_s[j*68 + k] = fc1w[i]; }
  if (tid < NB) dval_s[tid] = x[(bg0 + tid)*169 + 168];

  const float fc1b_r = fc1b[ln];
  const float fc2w_r = fc2w[ln];
  const float fc2b_r = fc2b[0];

  // FC head: all 8 waves, 2 batches each.
  auto fc_head = [&](int s){
    float o2[2];
    #pragma unroll
    for (int bi = 0; bi < 2; bi++){
      const int b = 2*wv8 + bi;
      float a1 = fc1b_r;
      #pragma unroll
      for (int k4 = 0; k4 < 16; k4++){
        const float* wp = &fc1w_s[ln*68 + k4*4];
        const float* hp = &Hlast[b][k4*4];
        a1 += wp[0]*hp[0] + wp[1]*hp[1] + wp[2]*hp[2] + wp[3]*hp[3];
      }
      a1 += dval_s[b] * fc1w_s[ln*68 + 64];
      float v = a1 * fc2w_r;
      #pragma unroll
      for (int off = 32; off > 0; off >>= 1) v += __shfl_xor(v, off);
      o2[bi] = v + fc2b_r;
    }
    if (ln == 0){
      #pragma unroll
      for (int bi = 0; bi < 2; bi++){
        const int b = 2*wv8 + bi;
        out[(bg0 + b)*24 + s] = o2[bi];
        win_s[s % WIN][b] = o2[bi];
      }
    }
  };

  if (isA){
    // ====== A: LSTM1 producer + LSTM2-L1 partial producer ======
    bf16x8 A1hi[4][2], A1lo[4][2], Ain1[4];
    bf16x8 A2hi[4][2], A2lo[4][2];                 // Wih2 (L1 ktiles of LSTM2)
    f32x4 b1c[4], b2c[4];
    #pragma unroll
    for (int e = 0; e < 4; e++){
      const int ja = 64*e + 16*wv + n;
      #pragma unroll
      for (int kt = 0; kt < 2; kt++){
        const float* pw = Whh1 + ja*64 + kt*32 + q*8;
        #pragma unroll
        for (int jj = 0; jj < 8; jj++){ short h,l; split_s(pw[jj], h, l); A1hi[e][kt][jj] = h; A1lo[e][kt][jj] = l; }
      }
      #pragma unroll
      for (int kt = 0; kt < 2; kt++){
        const float* pw = Wih2 + ja*64 + kt*32 + q*8;
        #pragma unroll
        for (int jj = 0; jj < 8; jj++){ short h,l; split_s(pw[jj], h, l); A2hi[e][kt][jj] = h; A2lo[e][kt][jj] = l; }
      }
      bf16x8 ain = {0,0,0,0,0,0,0,0};
      if (q == 0){ short wh, wl; split_s(Wih1[ja], wh, wl); ain[0] = wh; ain[1] = wh; ain[2] = wl; }
      Ain1[e] = ain;
      const int jc = 64*e + u0;
      #pragma unroll
      for (int r = 0; r < 4; r++){
        b1c[e][r] = bih1[jc+r] + bhh1[jc+r];
        b2c[e][r] = bih2[jc+r] + bhh2[jc+r];
      }
    }
    float c1[4];
    bf16x8 rh0, rl0, rh1, rl1;                     // hist regs for partial

    auto hloadA = [&](int t){
      const short* Hp = hblk + (size_t)t * 2048;
      rh0 = *(const bf16x8*)&Hp[ro];
      rl0 = *(const bf16x8*)&Hp[1024 + ro];
      rh1 = *(const bf16x8*)&Hp[512 + ro];
      rl1 = *(const bf16x8*)&Hp[1536 + ro];
    };
    // partial = b2c + L1kt0(hi*h, hi*l, lo*h) + L1kt1(same) -- order matches R9
    auto partial2 = [&](int pb){
      #pragma unroll
      for (int e = 0; e < 4; e++){
        f32x4 a = b2c[e];
        a = mfma16(A2hi[e][0], rh0, a);
        a = mfma16(A2hi[e][0], rl0, a);
        a = mfma16(A2lo[e][0], rh0, a);
        a = mfma16(A2hi[e][1], rh1, a);
        a = mfma16(A2hi[e][1], rl1, a);
        a = mfma16(A2lo[e][1], rh1, a);
        *(f32x4*)&pS[pb*PS_PB + pso + e*PS_E] = a;
      }
    };

    auto lstm1 = [&](int rb, int wb, int slot, int t, bool first){
      f32x4 acc[4];
      bf16x8 bin = {0,0,0,0,0,0,0,0};
      { float xv = win_s[slot][n]; uint32_t xh, xl; split_t(xv, xh, xl);
        if (q == 0){ bin[0] = (short)xh; bin[1] = (short)xl; bin[2] = (short)xh; } }
      if (first){
        #pragma unroll
        for (int e = 0; e < 4; e++) acc[e] = mfma16(Ain1[e], bin, b1c[e]);
      } else {
        bf16x8 Bh0 = *(const bf16x8*)&aS[FB(rb,0,0)+rdo];
        bf16x8 Bl0 = *(const bf16x8*)&aS[FB(rb,1,0)+rdo];
        bf16x8 Bh1 = *(const bf16x8*)&aS[FB(rb,0,1)+rdo];
        bf16x8 Bl1 = *(const bf16x8*)&aS[FB(rb,1,1)+rdo];
        #pragma unroll
        for (int e = 0; e < 4; e++){
          f32x4 a = b1c[e];
          a = mfma16(A1hi[e][0], Bh0, a);
          a = mfma16(A1hi[e][0], Bl0, a);
          a = mfma16(A1lo[e][0], Bh0, a);
          a = mfma16(A1hi[e][1], Bh1, a);
          a = mfma16(A1hi[e][1], Bl1, a);
          a = mfma16(A1lo[e][1], Bh1, a);
          a = mfma16(Ain1[e], bin, a);
          acc[e] = a;
        }
      }
      float hn[4];
      lstm_epi(acc, c1, hn);
      uint32_t ph[4], pl[4];
      #pragma unroll
      for (int r = 0; r < 4; r++) split_t(hn[r], ph[r], pl[r]);
      *(uint2*)&aS[FB(wb,0,kt_)+wro] = make_uint2(ph[0] | (ph[1]<<16), ph[2] | (ph[3]<<16));
      *(uint2*)&aS[FB(wb,1,kt_)+wro] = make_uint2(pl[0] | (pl[1]<<16), pl[2] | (pl[3]<<16));
      uint32_t sh[4], sl[4];
      #pragma unroll
      for (int r = 0; r < 4; r++){ bool pos = hn[r] > 0.0f; sh[r] = pos ? ph[r] : 0u; sl[r] = pos ? pl[r] : 0u; }
      short* Hp = hblk + (size_t)t * 2048;
      *(uint2*)&Hp[gwo]        = make_uint2(sh[0] | (sh[1]<<16), sh[2] | (sh[3]<<16));
      *(uint2*)&Hp[1024 + gwo] = make_uint2(sl[0] | (sl[1]<<16), sl[2] | (sl[3]<<16));
    };

    // ---- sweep 0: A(0) alone. 168 barriers. Last interval also makes
    //      partial(0,0) for B's first step.
    #pragma unroll
    for (int r = 0; r < 4; r++) c1[r] = 0.0f;
    for (int t = 0; t < WIN-1; t++){
      __syncthreads();
      lstm1(t & 1, (t & 1) ^ 1, t, t, t == 0);
    }
    __syncthreads();
    hloadA(0);                                     // hist(0,0) -- written at t=0
    lstm1(1, 0, WIN-1, WIN-1, false);
    partial2(0);
    #pragma unroll
    for (int r = 0; r < 4; r++) cS[u0 + r][n] = c1[r];

    // ---- fused sweeps sg=1..23. 170 barriers each (same as R9).
    for (int sg = 1; sg < NSTEPS; sg++){
      #pragma unroll
      for (int r = 0; r < 4; r++) c1[r] = 0.0f;
      int slot = sg;
      __syncthreads();                       // t=0
      hloadA(1);                             // hist(sg-1, 1)
      lstm1(0, 1, slot, 0, true);
      partial2(1);
      slot++;
      for (int t = 1; t < WIN-1; t++){
        __syncthreads();
        hloadA(t + 1);                       // hist(sg-1, t+1) -- still old-sweep
        lstm1(t & 1, (t & 1) ^ 1, slot, t, false);
        partial2((t + 1) & 1);
        slot++; if (slot == WIN) slot = 0;
      }
      __syncthreads();                       // (a): B does lstm2(167)
      hloadA(0);                             // hist(sg, 0) for partial(sg,0)
      __syncthreads();                       // (b): Hlast ready
      fc_head(sg - 1);
      __syncthreads();                       // (c): window updated
      lstm1(1, 0, slot, WIN-1, false);       // slot == sg-1
      partial2(0);                           // partial(sg, 0) -> pS[0]
      #pragma unroll
      for (int r = 0; r < 4; r++) cS[u0 + r][n] = c1[r];
    }

    // ---- final sweep: B(23) runs; A keeps producing partials. 169 barriers.
    for (int i = 0; i < WIN-1; i++){         // i = 0..166
      __syncthreads();
      hloadA(i + 1);                         // hist(23, i+1)
      partial2((i + 1) & 1);
    }
    __syncthreads();                         // (a)
    __syncthreads();                         // (b)
    fc_head(NSTEPS - 1);

  } else {
    // ====== B: LSTM2 L2-half + epilogue + FC consumer ======
    bf16x8 B2hi[4][2], B2lo[4][2];                 // Whh2 (L2 ktiles)
    #pragma unroll
    for (int e = 0; e < 4; e++){
      const int ja = 64*e + 16*wv + n;
      #pragma unroll
      for (int kt = 0; kt < 2; kt++){
        const float* pw = Whh2 + ja*64 + kt*32 + q*8;
        #pragma unroll
        for (int jj = 0; jj < 8; jj++){ short h,l; split_s(pw[jj], h, l); B2hi[e][kt][jj] = h; B2lo[e][kt][jj] = l; }
      }
    }
    float c2[4];

    auto lstm2 = [&](const short* Sr, int rb, short* Sw, int wb, int pb, bool last){
      f32x4 acc[4];
      #pragma unroll
      for (int e = 0; e < 4; e++) acc[e] = *(const f32x4*)&pS[pb*PS_PB + pso + e*PS_E];
      bf16x8 L2h0 = *(const bf16x8*)&Sr[FB(rb,0,0)+rdo];
      bf16x8 L2l0 = *(const bf16x8*)&Sr[FB(rb,1,0)+rdo];
      bf16x8 L2h1 = *(const bf16x8*)&Sr[FB(rb,0,1)+rdo];
      bf16x8 L2l1 = *(const bf16x8*)&Sr[FB(rb,1,1)+rdo];
      #pragma unroll
      for (int e = 0; e < 4; e++){
        f32x4 a = acc[e];
        a = mfma16(B2hi[e][0], L2h0, a);
        a = mfma16(B2hi[e][0], L2l0, a);
        a = mfma16(B2lo[e][0], L2h0, a);
        a = mfma16(B2hi[e][1], L2h1, a);
        a = mfma16(B2hi[e][1], L2l1, a);
        a = mfma16(B2lo[e][1], L2h1, a);
        acc[e] = a;
      }
      float hn[4];
      lstm_epi(acc, c2, hn);
      if (!last){
        uint32_t ph[4], pl[4];
        #pragma unroll
        for (int r = 0; r < 4; r++) split_t(hn[r], ph[r], pl[r]);
        *(uint2*)&Sw[FB(wb,0,kt_)+wro] = make_uint2(ph[0] | (ph[1]<<16), ph[2] | (ph[3]<<16));
        *(uint2*)&Sw[FB(wb,1,kt_)+wro] = make_uint2(pl[0] | (pl[1]<<16), pl[2] | (pl[3]<<16));
      } else {
        #pragma unroll
        for (int r = 0; r < 4; r++) Hlast[n][u0 + r] = fmaxf(hn[r], 0.0f);
      }
    };

    // ---- sweep 0: idle. 168 barriers.
    for (int i = 0; i < WIN; i++) __syncthreads();

    // ---- fused sweeps sg=1..23: B(sg-1). 170 barriers each.
    for (int sg = 1; sg < NSTEPS; sg++){
      __syncthreads();                       // t=0
      #pragma unroll
      for (int r = 0; r < 4; r++) c2[r] = cS[u0 + r][n];
      lstm2(aS, 0, bS, 1, 0, false);         // t=0: h2-init from aS[0], partial pS[0]
      for (int t = 1; t < WIN-1; t++){
        __syncthreads();
        lstm2(bS, t & 1, bS, (t & 1) ^ 1, t & 1, false);
      }
      __syncthreads();                       // (a)
      lstm2(bS, 1, bS, 0, 1, true);          // t=167 -> Hlast (pb = 167&1 = 1)
      __syncthreads();                       // (b)
      fc_head(sg - 1);
      __syncthreads();                       // (c)
    }

    // ---- final sweep: B(23). 169 barriers then FC.
    {
      __syncthreads();
      #pragma unroll
      for (int r = 0; r < 4; r++) c2[r] = cS[u0 + r][n];
      lstm2(aS, 0, bS, 1, 0, false);
      for (int t = 1; t < WIN-1; t++){
        __syncthreads();
        lstm2(bS, t & 1, bS, (t & 1) ^ 1, t & 1, false);
      }
      __syncthreads();
      lstm2(bS, 1, bS, 0, 1, true);
      __syncthreads();
      fc_head(NSTEPS - 1);
    }
  }
}

// ============================================================================
// Fallback (no workspace): replay scheme, 256 threads. Safety only.
// ============================================================================
__global__ __launch_bounds__(256, 1) void lstm_fallback_kernel(
  const float* __restrict__ x,    const float* __restrict__ Wih1, const float* __restrict__ Whh1,
  const float* __restrict__ bih1, const float* __restrict__ bhh1,
  const float* __restrict__ Wih2, const float* __restrict__ Whh2,
  const float* __restrict__ bih2, const float* __restrict__ bhh2,
  const float* __restrict__ fc1w, const float* __restrict__ fc1b,
  const float* __restrict__ fc2w, const float* __restrict__ fc2b,
  float* __restrict__ out)
{
  __shared__ __align__(16) short aS[2*2*2*FBLK];
  __shared__ __align__(16) short r1f[2*2*2*FBLK];
  __shared__ __align__(16) short rlf[2*2*2*FBLK];
  __shared__ float win_s[WIN][NB];
  __shared__ float Hlast[NB][68];
  __shared__ float fc1w_s[64*68];
  __shared__ float dval_s[NB];

  const int tid = threadIdx.x;
  const int wv  = tid >> 6;
  const int ln  = tid & 63;
  const int q   = ln >> 4;
  const int n   = ln & 15;
  const int bg0 = blockIdx.x * NB;
  const int u0  = 16*wv + 4*q;
  const int kt_  = u0 >> 5;
  const int q2_  = (u0 >> 3) & 3;
  const int jj0_ = u0 & 7;
  const int rdo  = q*FROW + n*8;
  const int wro  = q2_*FROW + n*8 + jj0_;

  for (int i = tid; i < WIN*NB; i += 256){ int t = i >> 4, b = i & 15; win_s[t][b] = x[(bg0 + b)*169 + t]; }
  for (int i = tid; i < 64*65; i += 256){ int j = i / 65, k = i % 65; fc1w_s[j*68 + k] = fc1w[i]; }
  if (tid < NB) dval_s[tid] = x[(bg0 + tid)*169 + 168];

  const float fc1b_r = fc1b[ln];
  const float fc2w_r = fc2w[ln];
  const float fc2b_r = fc2b[0];

  bf16x8 A1hi[4][2], A1lo[4][2], Ain1[4];
  bf16x8 A2hi[4][4], A2lo[4][4];
  f32x4 b1c[4], b2c[4];
  #pragma unroll
  for (int e = 0; e < 4; e++){
    const int ja = 64*e + 16*wv + n;
    #pragma unroll
    for (int kt = 0; kt < 2; kt++){
      const float* pw = Whh1 + ja*64 + kt*32 + q*8;
      #pragma unroll
      for (int jj = 0; jj < 8; jj++){ short h,l; split_s(pw[jj], h, l); A1hi[e][kt][jj] = h; A1lo[e][kt][jj] = l; }
    }
    #pragma unroll
    for (int kt = 0; kt < 4; kt++){
      const float* pw = (kt < 2 ? (Wih2 + ja*64 + kt*32) : (Whh2 + ja*64 + (kt-2)*32)) + q*8;
      #pragma unroll
      for (int jj = 0; jj < 8; jj++){ short h,l; split_s(pw[jj], h, l); A2hi[e][kt][jj] = h; A2lo[e][kt][jj] = l; }
    }
    bf16x8 ain = {0,0,0,0,0,0,0,0};
    if (q == 0){ short wh, wl; split_s(Wih1[ja], wh, wl); ain[0] = wh; ain[1] = wh; ain[2] = wl; }
    Ain1[e] = ain;
    const int jc = 64*e + u0;
    #pragma unroll
    for (int r = 0; r < 4; r++){
      b1c[e][r] = bih1[jc+r] + bhh1[jc+r];
      b2c[e][r] = bih2[jc+r] + bhh2[jc+r];
    }
  }

  float c1[4], c2[4], c1r[4];

  auto lstm1_step = [&](short* S, float* cst, int rb, int wb, int slot, bool relu_out){
    bf16x8 Bh0 = *(const bf16x8*)&S[FB(rb,0,0)+rdo];
    bf16x8 Bl0 = *(const bf16x8*)&S[FB(rb,1,0)+rdo];
    bf16x8 Bh1 = *(const bf16x8*)&S[FB(rb,0,1)+rdo];
    bf16x8 Bl1 = *(const bf16x8*)&S[FB(rb,1,1)+rdo];
    bf16x8 bin = {0,0,0,0,0,0,0,0};
    { float xv = win_s[slot][n]; uint32_t xh, xl; split_t(xv, xh, xl);
      if (q == 0){ bin[0] = (short)xh; bin[1] = (short)xl; bin[2] = (short)xh; } }
    f32x4 acc[4];
    #pragma unroll
    for (int e = 0; e < 4; e++){
      f32x4 a = b1c[e];
      a = mfma16(A1hi[e][0], Bh0, a);
      a = mfma16(A1hi[e][0], Bl0, a);
      a = mfma16(A1lo[e][0], Bh0, a);
      a = mfma16(A1hi[e][1], Bh1, a);
      a = mfma16(A1hi[e][1], Bl1, a);
      a = mfma16(A1lo[e][1], Bh1, a);
      a = mfma16(Ain1[e], bin, a);
      acc[e] = a;
    }
    float hn[4];
    lstm_epi(acc, cst, hn);
    uint32_t ph[4], pl[4];
    #pragma unroll
    for (int r = 0; r < 4; r++) split_t(hn[r], ph[r], pl[r]);
    *(uint2*)&S[FB(wb,0,kt_)+wro] = make_uint2(ph[0] | (ph[1]<<16), ph[2] | (ph[3]<<16));
    *(uint2*)&S[FB(wb,1,kt_)+wro] = make_uint2(pl[0] | (pl[1]<<16), pl[2] | (pl[3]<<16));
    if (relu_out){
      uint32_t sh[4], sl[4];
      #pragma unroll
      for (int r = 0; r < 4; r++){ bool pos = hn[r] > 0.0f; sh[r] = pos ? ph[r] : 0u; sl[r] = pos ? pl[r] : 0u; }
      *(uint2*)&rlf[FB(rb,0,kt_)+wro] = make_uint2(sh[0] | (sh[1]<<16), sh[2] | (sh[3]<<16));
      *(uint2*)&rlf[FB(rb,1,kt_)+wro] = make_uint2(sl[0] | (sl[1]<<16), sl[2] | (sl[3]<<16));
    }
  };

  auto lstm2_core = [&](bf16x8 L1h0, bf16x8 L1l0, bf16x8 L1h1, bf16x8 L1l1,
                        int rbuf, int wbuf, bool last){
    bf16x8 L2h0 = *(const bf16x8*)&aS[FB(rbuf,0,0)+rdo];
    bf16x8 L2l0 = *(const bf16x8*)&aS[FB(rbuf,1,0)+rdo];
    bf16x8 L2h1 = *(const bf16x8*)&aS[FB(rbuf,0,1)+rdo];
    bf16x8 L2l1 = *(const bf16x8*)&aS[FB(rbuf,1,1)+rdo];
    f32x4 acc[4];
    #pragma unroll
    for (int e = 0; e < 4; e++){
      f32x4 a = b2c[e];
      a = mfma16(A2hi[e][0], L1h0, a);
      a = mfma16(A2hi[e][0], L1l0, a);
      a = mfma16(A2lo[e][0], L1h0, a);
      a = mfma16(A2hi[e][1], L1h1, a);
      a = mfma16(A2hi[e][1], L1l1, a);
      a = mfma16(A2lo[e][1], L1h1, a);
      a = mfma16(A2hi[e][2], L2h0, a);
      a = mfma16(A2hi[e][2], L2l0, a);
      a = mfma16(A2lo[e][2], L2h0, a);
      a = mfma16(A2hi[e][3], L2h1, a);
      a = mfma16(A2hi[e][3], L2l1, a);
      a = mfma16(A2lo[e][3], L2h1, a);
      acc[e] = a;
    }
    float hn[4];
    lstm_epi(acc, c2, hn);
    if (!last){
      uint32_t ph[4], pl[4];
      #pragma unroll
      for (int r = 0; r < 4; r++) split_t(hn[r], ph[r], pl[r]);
      *(uint2*)&aS[FB(wbuf,0,kt_)+wro] = make_uint2(ph[0] | (ph[1]<<16), ph[2] | (ph[3]<<16));
      *(uint2*)&aS[FB(wbuf,1,kt_)+wro] = make_uint2(pl[0] | (pl[1]<<16), pl[2] | (pl[3]<<16));
    } else {
      #pragma unroll
      for (int r = 0; r < 4; r++) Hlast[n][u0 + r] = fmaxf(hn[r], 0.0f);
    }
  };

  for (int s = 0; s < NSTEPS; s++){
    { int* p = (int*)&aS[0];
      for (int i = tid; i < BUF_INTS; i += 256) p[i] = 0; }
    #pragma unroll
    for (int r = 0; r < 4; r++) c1[r] = 0.0f;
    int slot = s;
    for (int t = 0; t < WIN; t++){
      __syncthreads();
      lstm1_step(aS, c1, t & 1, (t & 1) ^ 1, slot, false);
      slot++; if (slot == WIN) slot = 0;
    }
    #pragma unroll
    for (int r = 0; r < 4; r++){ c2[r] = c1[r]; c1r[r] = 0.0f; }
    { int* p = (int*)&r1f[0];
      for (int i = tid; i < BUF_INTS; i += 256) p[i] = 0; }
    slot = s;
    __syncthreads();
    lstm1_step(r1f, c1r, 0, 1, slot, true);
    slot++;
    for (int i = 1; i < WIN; i++){
      __syncthreads();
      const int rb = i & 1, wb = rb ^ 1;
      lstm1_step(r1f, c1r, rb, wb, slot, true);
      bf16x8 L1h0 = *(const bf16x8*)&rlf[FB(wb,0,0)+rdo];
      bf16x8 L1l0 = *(const bf16x8*)&rlf[FB(wb,1,0)+rdo];
      bf16x8 L1h1 = *(const bf16x8*)&rlf[FB(wb,0,1)+rdo];
      bf16x8 L1l1 = *(const bf16x8*)&rlf[FB(wb,1,1)+rdo];
      lstm2_core(L1h0, L1l0, L1h1, L1l1, wb, rb, false);
      slot++; if (slot == WIN) slot = 0;
    }
    __syncthreads();
    {
      const int rb = (WIN - 1) & 1;
      bf16x8 L1h0 = *(const bf16x8*)&rlf[FB(rb,0,0)+rdo];
      bf16x8 L1l0 = *(const bf16x8*)&rlf[FB(rb,1,0)+rdo];
      bf16x8 L1h1 = *(const bf16x8*)&rlf[FB(rb,0,1)+rdo];
      bf16x8 L1l1 = *(const bf16x8*)&rlf[FB(rb,1,1)+rdo];
      lstm2_core(L1h0, L1l0, L1h1, L1l1, rb, 0, true);
    }
    __syncthreads();
    {
      float o4[4];
      #pragma unroll
      for (int bi = 0; bi < 4; bi++){
        const int b = 4*wv + bi;
        float a1 = fc1b_r;
        #pragma unroll
        for (int k4 = 0; k4 < 16; k4++){
          const float* wp = &fc1w_s[ln*68 + k4*4];
          const float* hp = &Hlast[b][k4*4];
          a1 += wp[0]*hp[0] + wp[1]*hp[1] + wp[2]*hp[2] + wp[3]*hp[3];
        }
        a1 += dval_s[b] * fc1w_s[ln*68 + 64];
        float v = a1 * fc2w_r;
        #pragma unroll
        for (int off = 32; off > 0; off >>= 1) v += __shfl_xor(v, off);
        o4[bi] = v + fc2b_r;
      }
      if (ln == 0){
        #pragma unroll
        for (int bi = 0; bi < 4; bi++){
          const int b = 4*wv + bi;
          out[(bg0 + b)*24 + s] = o4[bi];
          win_s[s % WIN][b] = o4[bi];
        }
      }
    }
  }
}

extern "C" void kernel_launch(void* const* d_in, const int* in_sizes, int n_in,
                              void* d_out, int out_size, void* d_ws, size_t ws_size,
                              hipStream_t stream) {
  (void)in_sizes; (void)n_in; (void)out_size;
  const size_t need = (size_t)NBLK * WIN * 2048 * sizeof(short);   // ~176 MB
  if (ws_size >= need){
    lstm_fused_kernel<<<dim3(NBLK), dim3(NT), 0, stream>>>(
        (const float*)d_in[0], (const float*)d_in[1], (const float*)d_in[2],
        (const float*)d_in[3], (const float*)d_in[4], (const float*)d_in[5],
        (const float*)d_in[6], (const float*)d_in[7], (const float*)d_in[8],
        (const float*)d_in[9], (const float*)d_in[10], (const float*)d_in[11],
        (const float*)d_in[12], (float*)d_out, (short*)d_ws);
  } else {
    lstm_fallback_kernel<<<dim3(NBLK), dim3(256), 0, stream>>>(
        (const float*)d_in[0], (const float*)d_in[1], (const float*)d_in[2],
        (const float*)d_in[3], (const float*)d_in[4], (const float*)d_in[5],
        (const float*)d_in[6], (const float*)d_in[7], (const float*)d_in[8],
        (const float*)d_in[9], (const float*)d_in[10], (const float*)d_in[11],
        (const float*)d_in[12], (float*)d_out);
  }
}

// Round 12
// 4855.198 us; speedup vs baseline: 1.2216x; 1.0760x over previous
//
#include <hip/hip_runtime.h>
#include <stdint.h>

#define NB 16
#define WIN 168
#define NSTEPS 24
#define NBLK (4096/NB)
#define NT 512

typedef __attribute__((ext_vector_type(8))) short bf16x8;
typedef __attribute__((ext_vector_type(4))) float f32x4;

#if __has_builtin(__builtin_amdgcn_rcpf)
#define RCPF(x) __builtin_amdgcn_rcpf(x)
#else
#define RCPF(x) (1.0f / (x))
#endif
#if __has_builtin(__builtin_amdgcn_exp2f)
#define EXP2F(x) __builtin_amdgcn_exp2f(x)
#else
#define EXP2F(x) __expf((x) * 0.6931471805599453f)
#endif

__device__ __forceinline__ float sigm(float x){
  return RCPF(1.0f + EXP2F(x * -1.4426950408889634f));
}
__device__ __forceinline__ float sigtanh(float a, float b){
  float A = EXP2F(a * -1.4426950408889634f);
  float B = EXP2F(fabsf(b) * -2.8853900817779268f);
  float t = (1.0f - B) * RCPF((1.0f + A) * (1.0f + B));
  uint32_t sb = __builtin_bit_cast(uint32_t, b) & 0x80000000u;
  return __builtin_bit_cast(float, __builtin_bit_cast(uint32_t, t) ^ sb);
}

__device__ __forceinline__ uint32_t bf_rn(float f){
  uint32_t u = __builtin_bit_cast(uint32_t, f);
  return (u + 0x7FFFu + ((u >> 16) & 1u)) >> 16;
}
__device__ __forceinline__ float bf_f(uint32_t s){
  return __builtin_bit_cast(float, s << 16);
}
__device__ __forceinline__ void split_t(float f, uint32_t& hi, uint32_t& lo){
  uint32_t u = __builtin_bit_cast(uint32_t, f);
  hi = u >> 16;
  lo = bf_rn(f - bf_f(hi));
}
__device__ __forceinline__ void split_s(float f, short& hi, short& lo){
  uint32_t h = bf_rn(f);
  hi = (short)h;
  lo = (short)bf_rn(f - bf_f(h));
}
__device__ __forceinline__ f32x4 mfma16(bf16x8 a, bf16x8 b, f32x4 c){
  return __builtin_amdgcn_mfma_f32_16x16x32_bf16(a, b, c, 0, 0, 0);
}

__device__ __forceinline__ void lstm_epi(const f32x4 acc[4], float c[4], float hn[4]){
  #pragma unroll
  for (int r = 0; r < 4; r++){
    float cn = __builtin_fmaf(sigm(acc[1][r]), c[r], sigtanh(acc[0][r], acc[2][r]));
    c[r] = cn;
    hn[r] = sigtanh(acc[3][r], cn);
  }
}

#define FROW 136
#define FBLK 544
#define FB(buf,hl,kt) ((((buf)*2 + (hl))*2 + (kt)) * FBLK)
#define BUF_INTS (2*FBLK)

// ============================================================================
// R12 = R9 (best known: 4958 us) + inner loops unrolled by 2 so every
// lstm1/lstm2 call passes COMPILE-TIME rb/wb. All LDS frag accesses become
// static `offset:` immediates off one base register (no per-iteration address
// VALU, no cndmask base selects, aligned operand tuples). Barrier counts per
// sweep preserved exactly (170 fused / 168 sweep0 / 169 final). Math frozen.
// ============================================================================
__global__ __launch_bounds__(NT, 2) void lstm_fused_kernel(
  const float* __restrict__ x,    const float* __restrict__ Wih1, const float* __restrict__ Whh1,
  const float* __restrict__ bih1, const float* __restrict__ bhh1,
  const float* __restrict__ Wih2, const float* __restrict__ Whh2,
  const float* __restrict__ bih2, const float* __restrict__ bhh2,
  const float* __restrict__ fc1w, const float* __restrict__ fc1b,
  const float* __restrict__ fc2w, const float* __restrict__ fc2b,
  float* __restrict__ out, short* __restrict__ hist)
{
  __shared__ __align__(16) short aS[2*2*2*FBLK];   // LSTM1 state dbuf
  __shared__ __align__(16) short bS[2*2*2*FBLK];   // LSTM2 state dbuf
  __shared__ float cS[64][16];                     // c1-final handoff A->B
  __shared__ float win_s[WIN][NB];
  __shared__ float Hlast[NB][68];
  __shared__ float fc1w_s[64*68];
  __shared__ float dval_s[NB];

  const int tid = threadIdx.x;
  const int wv8 = tid >> 6;          // 0..7
  const int wv  = wv8 & 3;           // role-local wave id 0..3
  const bool isA = (wv8 < 4);
  const int ln  = tid & 63;
  const int q   = ln >> 4;
  const int n   = ln & 15;
  const int bg0 = blockIdx.x * NB;
  const int u0  = 16*wv + 4*q;
  const int kt_  = u0 >> 5;
  const int q2_  = (u0 >> 3) & 3;
  const int jj0_ = u0 & 7;                          // {0,4}
  const int rdo  = q*FROW + n*8;                    // frag read offset
  const int wro  = q2_*FROW + n*8 + jj0_;           // frag write offset
  const int gwo  = kt_*512 + q2_*128 + n*8 + jj0_;  // hist write offset
  const int ro   = q*128 + n*8;                     // hist read offset
  short* __restrict__ hblk = hist + (size_t)blockIdx.x * WIN * 2048;

  for (int i = tid; i < WIN*NB; i += NT){ int t = i >> 4, b = i & 15; win_s[t][b] = x[(bg0 + b)*169 + t]; }
  for (int i = tid; i < 64*65; i += NT){ int j = i / 65, k = i % 65; fc1w_s[j*68 + k] = fc1w[i]; }
  if (tid < NB) dval_s[tid] = x[(bg0 + tid)*169 + 168];

  const float fc1b_r = fc1b[ln];
  const float fc2w_r = fc2w[ln];
  const float fc2b_r = fc2b[0];

  // FC head: all 8 waves, 2 batches each.
  auto fc_head = [&](int s){
    float o2[2];
    #pragma unroll
    for (int bi = 0; bi < 2; bi++){
      const int b = 2*wv8 + bi;
      float a1 = fc1b_r;
      #pragma unroll
      for (int k4 = 0; k4 < 16; k4++){
        const float* wp = &fc1w_s[ln*68 + k4*4];
        const float* hp = &Hlast[b][k4*4];
        a1 += wp[0]*hp[0] + wp[1]*hp[1] + wp[2]*hp[2] + wp[3]*hp[3];
      }
      a1 += dval_s[b] * fc1w_s[ln*68 + 64];
      float v = a1 * fc2w_r;
      #pragma unroll
      for (int off = 32; off > 0; off >>= 1) v += __shfl_xor(v, off);
      o2[bi] = v + fc2b_r;
    }
    if (ln == 0){
      #pragma unroll
      for (int bi = 0; bi < 2; bi++){
        const int b = 2*wv8 + bi;
        out[(bg0 + b)*24 + s] = o2[bi];
        win_s[s % WIN][b] = o2[bi];
      }
    }
  };

  if (isA){
    // =================== A-branch: LSTM1 producer ===================
    bf16x8 A1hi[4][2], A1lo[4][2], Ain1[4];
    f32x4 b1c[4];
    #pragma unroll
    for (int e = 0; e < 4; e++){
      const int ja = 64*e + 16*wv + n;
      #pragma unroll
      for (int kt = 0; kt < 2; kt++){
        const float* pw = Whh1 + ja*64 + kt*32 + q*8;
        #pragma unroll
        for (int jj = 0; jj < 8; jj++){ short h,l; split_s(pw[jj], h, l); A1hi[e][kt][jj] = h; A1lo[e][kt][jj] = l; }
      }
      bf16x8 ain = {0,0,0,0,0,0,0,0};
      if (q == 0){ short wh, wl; split_s(Wih1[ja], wh, wl); ain[0] = wh; ain[1] = wh; ain[2] = wl; }
      Ain1[e] = ain;
      const int jc = 64*e + u0;
      #pragma unroll
      for (int r = 0; r < 4; r++) b1c[e][r] = bih1[jc+r] + bhh1[jc+r];
    }
    float c1[4];

    // rb/wb/first must be compile-time at every call site.
    auto lstm1 = [&](int rb, int wb, int slot, int t, bool first){
      f32x4 acc[4];
      bf16x8 bin = {0,0,0,0,0,0,0,0};
      { float xv = win_s[slot][n]; uint32_t xh, xl; split_t(xv, xh, xl);
        if (q == 0){ bin[0] = (short)xh; bin[1] = (short)xl; bin[2] = (short)xh; } }
      if (first){
        #pragma unroll
        for (int e = 0; e < 4; e++) acc[e] = mfma16(Ain1[e], bin, b1c[e]);
      } else {
        bf16x8 Bh0 = *(const bf16x8*)&aS[FB(rb,0,0)+rdo];
        bf16x8 Bl0 = *(const bf16x8*)&aS[FB(rb,1,0)+rdo];
        bf16x8 Bh1 = *(const bf16x8*)&aS[FB(rb,0,1)+rdo];
        bf16x8 Bl1 = *(const bf16x8*)&aS[FB(rb,1,1)+rdo];
        #pragma unroll
        for (int e = 0; e < 4; e++){
          f32x4 a = b1c[e];
          a = mfma16(A1hi[e][0], Bh0, a);
          a = mfma16(A1hi[e][0], Bl0, a);
          a = mfma16(A1lo[e][0], Bh0, a);
          a = mfma16(A1hi[e][1], Bh1, a);
          a = mfma16(A1hi[e][1], Bl1, a);
          a = mfma16(A1lo[e][1], Bh1, a);
          a = mfma16(Ain1[e], bin, a);
          acc[e] = a;
        }
      }
      float hn[4];
      lstm_epi(acc, c1, hn);
      uint32_t ph[4], pl[4];
      #pragma unroll
      for (int r = 0; r < 4; r++) split_t(hn[r], ph[r], pl[r]);
      *(uint2*)&aS[FB(wb,0,kt_)+wro] = make_uint2(ph[0] | (ph[1]<<16), ph[2] | (ph[3]<<16));
      *(uint2*)&aS[FB(wb,1,kt_)+wro] = make_uint2(pl[0] | (pl[1]<<16), pl[2] | (pl[3]<<16));
      uint32_t sh[4], sl[4];
      #pragma unroll
      for (int r = 0; r < 4; r++){ bool pos = hn[r] > 0.0f; sh[r] = pos ? ph[r] : 0u; sl[r] = pos ? pl[r] : 0u; }
      short* Hp = hblk + (size_t)t * 2048;
      *(uint2*)&Hp[gwo]        = make_uint2(sh[0] | (sh[1]<<16), sh[2] | (sh[3]<<16));
      *(uint2*)&Hp[1024 + gwo] = make_uint2(sl[0] | (sl[1]<<16), sl[2] | (sl[3]<<16));
    };

    // ---- sweep 0: A(0) alone. 168 barriers. slot == t.
    #pragma unroll
    for (int r = 0; r < 4; r++) c1[r] = 0.0f;
    __syncthreads();
    lstm1(0, 1, 0, 0, true);                          // t=0
    for (int t = 1; t < WIN-1; t += 2){
      __syncthreads();
      lstm1(1, 0, t, t, false);                       // odd t
      __syncthreads();
      lstm1(0, 1, t+1, t+1, false);                   // even t+1
    }
    __syncthreads();
    lstm1(1, 0, WIN-1, WIN-1, false);                 // t=167 -> final h1 in buf0
    #pragma unroll
    for (int r = 0; r < 4; r++) cS[u0 + r][n] = c1[r];

    // ---- fused sweeps sg=1..23. 170 barriers each.
    for (int sg = 1; sg < NSTEPS; sg++){
      #pragma unroll
      for (int r = 0; r < 4; r++) c1[r] = 0.0f;
      int slot = sg;
      __syncthreads();                                // t=0
      lstm1(0, 1, slot, 0, true);
      slot++;
      for (int t = 1; t < WIN-1; t += 2){
        __syncthreads();
        lstm1(1, 0, slot, t, false);                  // odd t
        slot++; if (slot == WIN) slot = 0;
        __syncthreads();
        lstm1(0, 1, slot, t+1, false);                // even t+1
        slot++; if (slot == WIN) slot = 0;
      }
      __syncthreads();                                // (a): B does lstm2(167)
      __syncthreads();                                // (b): Hlast ready
      fc_head(sg - 1);
      __syncthreads();                                // (c): window updated
      lstm1(1, 0, slot, WIN-1, false);                // t=167, slot == sg-1
      #pragma unroll
      for (int r = 0; r < 4; r++) cS[u0 + r][n] = c1[r];
    }

    // ---- final sweep: B(23) alone. 169 barriers then FC.
    for (int i = 0; i < WIN + 1; i++) __syncthreads();
    fc_head(NSTEPS - 1);

  } else {
    // =================== B-branch: LSTM2 consumer ===================
    bf16x8 A2hi[4][4], A2lo[4][4];
    f32x4 b2c[4];
    #pragma unroll
    for (int e = 0; e < 4; e++){
      const int ja = 64*e + 16*wv + n;
      #pragma unroll
      for (int kt = 0; kt < 4; kt++){
        const float* pw = (kt < 2 ? (Wih2 + ja*64 + kt*32) : (Whh2 + ja*64 + (kt-2)*32)) + q*8;
        #pragma unroll
        for (int jj = 0; jj < 8; jj++){ short h,l; split_s(pw[jj], h, l); A2hi[e][kt][jj] = h; A2lo[e][kt][jj] = l; }
      }
      const int jc = 64*e + u0;
      #pragma unroll
      for (int r = 0; r < 4; r++) b2c[e][r] = bih2[jc+r] + bhh2[jc+r];
    }
    float c2[4];
    bf16x8 ch0, cl0, ch1, cl1, nh0, nl0, nh1, nl1;

    auto loadc = [&](int t){
      const short* Hp = hblk + (size_t)t * 2048;
      ch0 = *(const bf16x8*)&Hp[ro];
      cl0 = *(const bf16x8*)&Hp[1024 + ro];
      ch1 = *(const bf16x8*)&Hp[512 + ro];
      cl1 = *(const bf16x8*)&Hp[1536 + ro];
    };
    auto loadn = [&](int t){
      const short* Hp = hblk + (size_t)t * 2048;
      nh0 = *(const bf16x8*)&Hp[ro];
      nl0 = *(const bf16x8*)&Hp[1024 + ro];
      nh1 = *(const bf16x8*)&Hp[512 + ro];
      nl1 = *(const bf16x8*)&Hp[1536 + ro];
    };
    auto shift = [&](){ ch0 = nh0; cl0 = nl0; ch1 = nh1; cl1 = nl1; };

    // Sr/rb/Sw/wb must be compile-time at every call site.
    auto lstm2 = [&](const short* Sr, int rb, short* Sw, int wb, bool last){
      bf16x8 L2h0 = *(const bf16x8*)&Sr[FB(rb,0,0)+rdo];
      bf16x8 L2l0 = *(const bf16x8*)&Sr[FB(rb,1,0)+rdo];
      bf16x8 L2h1 = *(const bf16x8*)&Sr[FB(rb,0,1)+rdo];
      bf16x8 L2l1 = *(const bf16x8*)&Sr[FB(rb,1,1)+rdo];
      f32x4 acc[4];
      #pragma unroll
      for (int e = 0; e < 4; e++){
        f32x4 a = b2c[e];
        a = mfma16(A2hi[e][0], ch0, a);
        a = mfma16(A2hi[e][0], cl0, a);
        a = mfma16(A2lo[e][0], ch0, a);
        a = mfma16(A2hi[e][1], ch1, a);
        a = mfma16(A2hi[e][1], cl1, a);
        a = mfma16(A2lo[e][1], ch1, a);
        a = mfma16(A2hi[e][2], L2h0, a);
        a = mfma16(A2hi[e][2], L2l0, a);
        a = mfma16(A2lo[e][2], L2h0, a);
        a = mfma16(A2hi[e][3], L2h1, a);
        a = mfma16(A2hi[e][3], L2l1, a);
        a = mfma16(A2lo[e][3], L2h1, a);
        acc[e] = a;
      }
      float hn[4];
      lstm_epi(acc, c2, hn);
      if (!last){
        uint32_t ph[4], pl[4];
        #pragma unroll
        for (int r = 0; r < 4; r++) split_t(hn[r], ph[r], pl[r]);
        *(uint2*)&Sw[FB(wb,0,kt_)+wro] = make_uint2(ph[0] | (ph[1]<<16), ph[2] | (ph[3]<<16));
        *(uint2*)&Sw[FB(wb,1,kt_)+wro] = make_uint2(pl[0] | (pl[1]<<16), pl[2] | (pl[3]<<16));
      } else {
        #pragma unroll
        for (int r = 0; r < 4; r++) Hlast[n][u0 + r] = fmaxf(hn[r], 0.0f);
      }
    };

    // ---- sweep 0: idle. 168 barriers.
    for (int i = 0; i < WIN; i++) __syncthreads();

    // ---- fused sweeps sg=1..23: B(sg-1). 170 barriers each.
    for (int sg = 1; sg < NSTEPS; sg++){
      loadc(0);                              // sweep seed (drains at t=0 barrier;
      loadn(1);                              // A rewrites slot 0 in interval 0)
      __syncthreads();                       // t=0
      #pragma unroll
      for (int r = 0; r < 4; r++) c2[r] = cS[u0 + r][n];
      lstm2(aS, 0, bS, 1, false);            // t=0: h2-init from aS[0]
      shift();
      for (int t = 1; t < WIN-1; t += 2){
        __syncthreads();
        loadn(t + 1);                        // hoisted prefetch (R9)
        lstm2(bS, 1, bS, 0, false);          // odd t
        shift();
        __syncthreads();
        loadn(t + 2);                        // t+2 <= 167
        lstm2(bS, 0, bS, 1, false);          // even t+1
        shift();
      }
      __syncthreads();                       // (a)
      lstm2(bS, 1, bS, 0, true);             // t=167 -> Hlast
      __syncthreads();                       // (b)
      fc_head(sg - 1);
      __syncthreads();                       // (c)
    }

    // ---- final sweep: B(23). 169 barriers then FC.
    {
      loadc(0);
      loadn(1);
      __syncthreads();
      #pragma unroll
      for (int r = 0; r < 4; r++) c2[r] = cS[u0 + r][n];
      lstm2(aS, 0, bS, 1, false);
      shift();
      for (int t = 1; t < WIN-1; t += 2){
        __syncthreads();
        loadn(t + 1);
        lstm2(bS, 1, bS, 0, false);
        shift();
        __syncthreads();
        loadn(t + 2);
        lstm2(bS, 0, bS, 1, false);
        shift();
      }
      __syncthreads();
      lstm2(bS, 1, bS, 0, true);             // t=167
      __syncthreads();
      fc_head(NSTEPS - 1);
    }
  }
}

// ============================================================================
// Fallback (no workspace): replay scheme, 256 threads. Safety only.
// ============================================================================
__global__ __launch_bounds__(256, 1) void lstm_fallback_kernel(
  const float* __restrict__ x,    const float* __restrict__ Wih1, const float* __restrict__ Whh1,
  const float* __restrict__ bih1, const float* __restrict__ bhh1,
  const float* __restrict__ Wih2, const float* __restrict__ Whh2,
  const float* __restrict__ bih2, const float* __restrict__ bhh2,
  const float* __restrict__ fc1w, const float* __restrict__ fc1b,
  const float* __restrict__ fc2w, const float* __restrict__ fc2b,
  float* __restrict__ out)
{
  __shared__ __align__(16) short aS[2*2*2*FBLK];
  __shared__ __align__(16) short r1f[2*2*2*FBLK];
  __shared__ __align__(16) short rlf[2*2*2*FBLK];
  __shared__ float win_s[WIN][NB];
  __shared__ float Hlast[NB][68];
  __shared__ float fc1w_s[64*68];
  __shared__ float dval_s[NB];

  const int tid = threadIdx.x;
  const int wv  = tid >> 6;
  const int ln  = tid & 63;
  const int q   = ln >> 4;
  const int n   = ln & 15;
  const int bg0 = blockIdx.x * NB;
  const int u0  = 16*wv + 4*q;
  const int kt_  = u0 >> 5;
  const int q2_  = (u0 >> 3) & 3;
  const int jj0_ = u0 & 7;
  const int rdo  = q*FROW + n*8;
  const int wro  = q2_*FROW + n*8 + jj0_;

  for (int i = tid; i < WIN*NB; i += 256){ int t = i >> 4, b = i & 15; win_s[t][b] = x[(bg0 + b)*169 + t]; }
  for (int i = tid; i < 64*65; i += 256){ int j = i / 65, k = i % 65; fc1w_s[j*68 + k] = fc1w[i]; }
  if (tid < NB) dval_s[tid] = x[(bg0 + tid)*169 + 168];

  const float fc1b_r = fc1b[ln];
  const float fc2w_r = fc2w[ln];
  const float fc2b_r = fc2b[0];

  bf16x8 A1hi[4][2], A1lo[4][2], Ain1[4];
  bf16x8 A2hi[4][4], A2lo[4][4];
  f32x4 b1c[4], b2c[4];
  #pragma unroll
  for (int e = 0; e < 4; e++){
    const int ja = 64*e + 16*wv + n;
    #pragma unroll
    for (int kt = 0; kt < 2; kt++){
      const float* pw = Whh1 + ja*64 + kt*32 + q*8;
      #pragma unroll
      for (int jj = 0; jj < 8; jj++){ short h,l; split_s(pw[jj], h, l); A1hi[e][kt][jj] = h; A1lo[e][kt][jj] = l; }
    }
    #pragma unroll
    for (int kt = 0; kt < 4; kt++){
      const float* pw = (kt < 2 ? (Wih2 + ja*64 + kt*32) : (Whh2 + ja*64 + (kt-2)*32)) + q*8;
      #pragma unroll
      for (int jj = 0; jj < 8; jj++){ short h,l; split_s(pw[jj], h, l); A2hi[e][kt][jj] = h; A2lo[e][kt][jj] = l; }
    }
    bf16x8 ain = {0,0,0,0,0,0,0,0};
    if (q == 0){ short wh, wl; split_s(Wih1[ja], wh, wl); ain[0] = wh; ain[1] = wh; ain[2] = wl; }
    Ain1[e] = ain;
    const int jc = 64*e + u0;
    #pragma unroll
    for (int r = 0; r < 4; r++){
      b1c[e][r] = bih1[jc+r] + bhh1[jc+r];
      b2c[e][r] = bih2[jc+r] + bhh2[jc+r];
    }
  }

  float c1[4], c2[4], c1r[4];

  auto lstm1_step = [&](short* S, float* cst, int rb, int wb, int slot, bool relu_out){
    bf16x8 Bh0 = *(const bf16x8*)&S[FB(rb,0,0)+rdo];
    bf16x8 Bl0 = *(const bf16x8*)&S[FB(rb,1,0)+rdo];
    bf16x8 Bh1 = *(const bf16x8*)&S[FB(rb,0,1)+rdo];
    bf16x8 Bl1 = *(const bf16x8*)&S[FB(rb,1,1)+rdo];
    bf16x8 bin = {0,0,0,0,0,0,0,0};
    { float xv = win_s[slot][n]; uint32_t xh, xl; split_t(xv, xh, xl);
      if (q == 0){ bin[0] = (short)xh; bin[1] = (short)xl; bin[2] = (short)xh; } }
    f32x4 acc[4];
    #pragma unroll
    for (int e = 0; e < 4; e++){
      f32x4 a = b1c[e];
      a = mfma16(A1hi[e][0], Bh0, a);
      a = mfma16(A1hi[e][0], Bl0, a);
      a = mfma16(A1lo[e][0], Bh0, a);
      a = mfma16(A1hi[e][1], Bh1, a);
      a = mfma16(A1hi[e][1], Bl1, a);
      a = mfma16(A1lo[e][1], Bh1, a);
      a = mfma16(Ain1[e], bin, a);
      acc[e] = a;
    }
    float hn[4];
    lstm_epi(acc, cst, hn);
    uint32_t ph[4], pl[4];
    #pragma unroll
    for (int r = 0; r < 4; r++) split_t(hn[r], ph[r], pl[r]);
    *(uint2*)&S[FB(wb,0,kt_)+wro] = make_uint2(ph[0] | (ph[1]<<16), ph[2] | (ph[3]<<16));
    *(uint2*)&S[FB(wb,1,kt_)+wro] = make_uint2(pl[0] | (pl[1]<<16), pl[2] | (pl[3]<<16));
    if (relu_out){
      uint32_t sh[4], sl[4];
      #pragma unroll
      for (int r = 0; r < 4; r++){ bool pos = hn[r] > 0.0f; sh[r] = pos ? ph[r] : 0u; sl[r] = pos ? pl[r] : 0u; }
      *(uint2*)&rlf[FB(rb,0,kt_)+wro] = make_uint2(sh[0] | (sh[1]<<16), sh[2] | (sh[3]<<16));
      *(uint2*)&rlf[FB(rb,1,kt_)+wro] = make_uint2(sl[0] | (sl[1]<<16), sl[2] | (sl[3]<<16));
    }
  };

  auto lstm2_core = [&](bf16x8 L1h0, bf16x8 L1l0, bf16x8 L1h1, bf16x8 L1l1,
                        int rbuf, int wbuf, bool last){
    bf16x8 L2h0 = *(const bf16x8*)&aS[FB(rbuf,0,0)+rdo];
    bf16x8 L2l0 = *(const bf16x8*)&aS[FB(rbuf,1,0)+rdo];
    bf16x8 L2h1 = *(const bf16x8*)&aS[FB(rbuf,0,1)+rdo];
    bf16x8 L2l1 = *(const bf16x8*)&aS[FB(rbuf,1,1)+rdo];
    f32x4 acc[4];
    #pragma unroll
    for (int e = 0; e < 4; e++){
      f32x4 a = b2c[e];
      a = mfma16(A2hi[e][0], L1h0, a);
      a = mfma16(A2hi[e][0], L1l0, a);
      a = mfma16(A2lo[e][0], L1h0, a);
      a = mfma16(A2hi[e][1], L1h1, a);
      a = mfma16(A2hi[e][1], L1l1, a);
      a = mfma16(A2lo[e][1], L1h1, a);
      a = mfma16(A2hi[e][2], L2h0, a);
      a = mfma16(A2hi[e][2], L2l0, a);
      a = mfma16(A2lo[e][2], L2h0, a);
      a = mfma16(A2hi[e][3], L2h1, a);
      a = mfma16(A2hi[e][3], L2l1, a);
      a = mfma16(A2lo[e][3], L2h1, a);
      acc[e] = a;
    }
    float hn[4];
    lstm_epi(acc, c2, hn);
    if (!last){
      uint32_t ph[4], pl[4];
      #pragma unroll
      for (int r = 0; r < 4; r++) split_t(hn[r], ph[r], pl[r]);
      *(uint2*)&aS[FB(wbuf,0,kt_)+wro] = make_uint2(ph[0] | (ph[1]<<16), ph[2] | (ph[3]<<16));
      *(uint2*)&aS[FB(wbuf,1,kt_)+wro] = make_uint2(pl[0] | (pl[1]<<16), pl[2] | (pl[3]<<16));
    } else {
      #pragma unroll
      for (int r = 0; r < 4; r++) Hlast[n][u0 + r] = fmaxf(hn[r], 0.0f);
    }
  };

  for (int s = 0; s < NSTEPS; s++){
    { int* p = (int*)&aS[0];
      for (int i = tid; i < BUF_INTS; i += 256) p[i] = 0; }
    #pragma unroll
    for (int r = 0; r < 4; r++) c1[r] = 0.0f;
    int slot = s;
    for (int t = 0; t < WIN; t++){
      __syncthreads();
      lstm1_step(aS, c1, t & 1, (t & 1) ^ 1, slot, false);
      slot++; if (slot == WIN) slot = 0;
    }
    #pragma unroll
    for (int r = 0; r < 4; r++){ c2[r] = c1[r]; c1r[r] = 0.0f; }
    { int* p = (int*)&r1f[0];
      for (int i = tid; i < BUF_INTS; i += 256) p[i] = 0; }
    slot = s;
    __syncthreads();
    lstm1_step(r1f, c1r, 0, 1, slot, true);
    slot++;
    for (int i = 1; i < WIN; i++){
      __syncthreads();
      const int rb = i & 1, wb = rb ^ 1;
      lstm1_step(r1f, c1r, rb, wb, slot, true);
      bf16x8 L1h0 = *(const bf16x8*)&rlf[FB(wb,0,0)+rdo];
      bf16x8 L1l0 = *(const bf16x8*)&rlf[FB(wb,1,0)+rdo];
      bf16x8 L1h1 = *(const bf16x8*)&rlf[FB(wb,0,1)+rdo];
      bf16x8 L1l1 = *(const bf16x8*)&rlf[FB(wb,1,1)+rdo];
      lstm2_core(L1h0, L1l0, L1h1, L1l1, wb, rb, false);
      slot++; if (slot == WIN) slot = 0;
    }
    __syncthreads();
    {
      const int rb = (WIN - 1) & 1;
      bf16x8 L1h0 = *(const bf16x8*)&rlf[FB(rb,0,0)+rdo];
      bf16x8 L1l0 = *(const bf16x8*)&rlf[FB(rb,1,0)+rdo];
      bf16x8 L1h1 = *(const bf16x8*)&rlf[FB(rb,0,1)+rdo];
      bf16x8 L1l1 = *(const bf16x8*)&rlf[FB(rb,1,1)+rdo];
      lstm2_core(L1h0, L1l0, L1h1, L1l1, rb, 0, true);
    }
    __syncthreads();
    {
      float o4[4];
      #pragma unroll
      for (int bi = 0; bi < 4; bi++){
        const int b = 4*wv + bi;
        float a1 = fc1b_r;
        #pragma unroll
        for (int k4 = 0; k4 < 16; k4++){
          const float* wp = &fc1w_s[ln*68 + k4*4];
          const float* hp = &Hlast[b][k4*4];
          a1 += wp[0]*hp[0] + wp[1]*hp[1] + wp[2]*hp[2] + wp[3]*hp[3];
        }
        a1 += dval_s[b] * fc1w_s[ln*68 + 64];
        float v = a1 * fc2w_r;
        #pragma unroll
        for (int off = 32; off > 0; off >>= 1) v += __shfl_xor(v, off);
        o4[bi] = v + fc2b_r;
      }
      if (ln == 0){
        #pragma unroll
        for (int bi = 0; bi < 4; bi++){
          const int b = 4*wv + bi;
          out[(bg0 + b)*24 + s] = o4[bi];
          win_s[s % WIN][b] = o4[bi];
        }
      }
    }
  }
}

extern "C" void kernel_launch(void* const* d_in, const int* in_sizes, int n_in,
                              void* d_out, int out_size, void* d_ws, size_t ws_size,
                              hipStream_t stream) {
  (void)in_sizes; (void)n_in; (void)out_size;
  const size_t need = (size_t)NBLK * WIN * 2048 * sizeof(short);   // ~176 MB
  if (ws_size >= need){
    lstm_fused_kernel<<<dim3(NBLK), dim3(NT), 0, stream>>>(
        (const float*)d_in[0], (const float*)d_in[1], (const float*)d_in[2],
        (const float*)d_in[3], (const float*)d_in[4], (const float*)d_in[5],
        (const float*)d_in[6], (const float*)d_in[7], (const float*)d_in[8],
        (const float*)d_in[9], (const float*)d_in[10], (const float*)d_in[11],
        (const float*)d_in[12], (float*)d_out, (short*)d_ws);
  } else {
    lstm_fallback_kernel<<<dim3(NBLK), dim3(256), 0, stream>>>(
        (const float*)d_in[0], (const float*)d_in[1], (const float*)d_in[2],
        (const float*)d_in[3], (const float*)d_in[4], (const float*)d_in[5],
        (const float*)d_in[6], (const float*)d_in[7], (const float*)d_in[8],
        (const float*)d_in[9], (const float*)d_in[10], (const float*)d_in[11],
        (const float*)d_in[12], (float*)d_out);
  }
}